// Round 4
// baseline (126.279 us; speedup 1.0000x reference)
//
#include <hip/hip_runtime.h>
#include <math.h>

#define D_FEAT 64
typedef _Float16 v8h __attribute__((ext_vector_type(8)));
typedef float v4f __attribute__((ext_vector_type(4)));
typedef _Float16 h2 __attribute__((ext_vector_type(2)));

__device__ __forceinline__ v8h u2h8(uint4 u) { v8h v; __builtin_memcpy(&v, &u, 16); return v; }
__device__ __forceinline__ unsigned pkh(float a, float b) {
    h2 r = {(_Float16)a, (_Float16)b};           // RNE, numerics match old f16 relay
    unsigned u; __builtin_memcpy(&u, &r, 4); return u;
}

// ---- K0 (merged): blocks [0,nb_prep): per-node rsqrt-norm + f16 copy of x.
//      blocks [nb_prep,..): CSR row offsets via boundary scatter (rows sorted).
__global__ __launch_bounds__(256)
void agnn_prep(const float* __restrict__ x, float* __restrict__ rn,
               uint2* __restrict__ xh, const int* __restrict__ edge_row,
               int* __restrict__ row_ptr, int n_nodes, int n_edges, int nb_prep) {
    if ((int)blockIdx.x < nb_prep) {
        int t = blockIdx.x * blockDim.x + threadIdx.x;
        int node = t >> 4;
        if (node >= n_nodes) return;
        int l4 = t & 15;
        float4 v = ((const float4*)x)[node * 16 + l4];
        float ss = v.x*v.x + v.y*v.y + v.z*v.z + v.w*v.w;
        #pragma unroll
        for (int off = 1; off < 16; off <<= 1) ss += __shfl_xor(ss, off, 64);
        if (l4 == 0) rn[node] = ss > 0.f ? rsqrtf(ss) : 0.f;
        h2 h0 = {(_Float16)v.x, (_Float16)v.y};
        h2 h1 = {(_Float16)v.z, (_Float16)v.w};
        uint2 u;
        __builtin_memcpy(&u.x, &h0, 4);
        __builtin_memcpy(&u.y, &h1, 4);
        xh[node * 16 + l4] = u;
    } else {
        int e = (blockIdx.x - nb_prep) * blockDim.x + threadIdx.x;
        if (e >= n_edges) return;
        int r1 = edge_row[e];
        int r0 = (e == 0) ? -1 : edge_row[e - 1];
        for (int r = r0 + 1; r <= r1; ++r) row_ptr[r] = e;
        if (e == n_edges - 1)
            for (int r = r1 + 1; r <= n_nodes; ++r) row_ptr[r] = n_edges;
    }
}

// ---- K1: block-sparse flash-style fused kernel, 2 cooperating waves/tile ----
// SWAPPED QK^T: z = mfma(Xc, Q) (gathered regs are already a valid A-operand,
// Q regs a valid B-operand) -> lane holds P[row=lo4][4 edges].  This makes the
// row mask a per-lane interval [blo,bhi), and the P->PV-A-fragment relay is
// 8 shuffles + selects IN-REGISTER instead of an LDS round trip, deleting the
// 1280B/wave P buffer.  Rationale: measured occupancy across r0/r2/r3 matches
// an effective 64KB LDS pool (8/10/10 waves per CU) -> LDS/wave is the
// residency limiter; 9216B/block lifts 5 -> 7 blocks/CU (14 waves).
// Layouts per guide Sec.3: C/D col=lane&15,row=quad*4+reg; A m=lane&15,k=quad*8+j.
#define XCP_PITCH 144
#define WAVE_LDS  (32 * XCP_PITCH)   /* 4608 B: feature transpose buffer only */

__global__ __launch_bounds__(128)
void agnn_fused(const float* __restrict__ beta_p,
                const int* __restrict__ edge_col,
                const int* __restrict__ row_ptr,
                const float* __restrict__ rn,
                const uint4* __restrict__ xh4,
                float* __restrict__ out, int n_nodes) {
    __shared__ char lds_raw[2 * WAVE_LDS];
    int wid  = threadIdx.x >> 6;
    int lane = threadIdx.x & 63;
    int q    = lane >> 4;
    int lo4  = lane & 15;
    char* XCP = lds_raw + wid * WAVE_LDS;

    int tile = blockIdx.x;
    int t0 = tile * 16;
    if (t0 >= n_nodes) return;

    int qnode = t0 + lo4; if (qnode >= n_nodes) qnode = n_nodes - 1;
    v8h a0 = u2h8(xh4[(size_t)qnode * 8 + q]);       // Q feats [8q..8q+8)
    v8h a1 = u2h8(xh4[(size_t)qnode * 8 + 4 + q]);   // Q feats [32+8q..)

    float beta  = beta_p[0];
    float shift = fabsf(beta);
    // Per-lane row (= lo4): scaled inverse norm + edge-slot interval.
    float brn = beta * rn[qnode];
    int es   = row_ptr[t0];
    int tend = t0 + 16; if (tend > n_nodes) tend = n_nodes;
    int L    = row_ptr[tend] - es;
    int blo  = row_ptr[min(t0 + lo4,     n_nodes)] - es;
    int bhi  = row_ptr[min(t0 + lo4 + 1, n_nodes)] - es;

    v4f o0 = {0,0,0,0}, o1 = {0,0,0,0}, o2 = {0,0,0,0}, o3 = {0,0,0,0};
    float lsum = 0.f;
    unsigned int selp = (lo4 & 1) ? 0x07060302u : 0x05040100u;
    int srcA = ((q & 1) << 5) + lo4;   // P-dance source lanes (see table below)
    int srcB = srcA + 16;

    int nch  = (L + 31) >> 5;
    int nchw = (nch > wid) ? ((nch - wid + 1) >> 1) : 0;  // chunks for this wave
    if (nchw > 0) {
        // Prologue: this wave's chunk 0 (global chunk index = wid).
        int cc0, cc1;
        {
            int i0 = (wid << 5) + lo4, i1 = i0 + 16;
            cc0 = edge_col[es + (i0 < L ? i0 : 0)];
            cc1 = edge_col[es + (i1 < L ? i1 : 0)];
        }
        float rc0 = rn[cc0], rc1 = rn[cc1];
        uint4 A00 = xh4[(size_t)cc0 * 8 + q];
        uint4 A01 = xh4[(size_t)cc0 * 8 + 4 + q];
        uint4 A10 = xh4[(size_t)cc1 * 8 + q];
        uint4 A11 = xh4[(size_t)cc1 * 8 + 4 + q];

        for (int k = 0; k < nchw; ++k) {
            int base = (wid + 2 * k) << 5;
            bool more = (k + 1) < nchw;

            // Prefetch this wave's next chunk (+64 edges) column indices.
            int nc0, nc1;
            if (more) {
                int i0 = base + 64 + lo4, i1 = i0 + 16;
                nc0 = edge_col[es + (i0 < L ? i0 : 0)];
                nc1 = edge_col[es + (i1 < L ? i1 : 0)];
            } else { nc0 = cc0; nc1 = cc1; }

            // Swapped QK^T: z0[reg] = S^T[edge base+4q+reg][row lo4],
            //               z1[reg] = S^T[edge base+16+4q+reg][row lo4].
            v4f z0 = {0,0,0,0};
            z0 = __builtin_amdgcn_mfma_f32_16x16x32_f16(u2h8(A00), a0, z0, 0, 0, 0);
            z0 = __builtin_amdgcn_mfma_f32_16x16x32_f16(u2h8(A01), a1, z0, 0, 0, 0);
            v4f z1 = {0,0,0,0};
            z1 = __builtin_amdgcn_mfma_f32_16x16x32_f16(u2h8(A10), a0, z1, 0, 0, 0);
            z1 = __builtin_amdgcn_mfma_f32_16x16x32_f16(u2h8(A11), a1, z1, 0, 0, 0);

            // Stage features to XCP (feat-pair-major) for the PV B-operand.
            {
                unsigned int colA = lo4 * 4, colB = (16 + lo4) * 4;
                char* pA = XCP + (4 * q) * XCP_PITCH;
                char* pB = XCP + (16 + 4 * q) * XCP_PITCH;
                *(unsigned int*)(pA + 0 * XCP_PITCH + colA) = A00.x;
                *(unsigned int*)(pA + 1 * XCP_PITCH + colA) = A00.y;
                *(unsigned int*)(pA + 2 * XCP_PITCH + colA) = A00.z;
                *(unsigned int*)(pA + 3 * XCP_PITCH + colA) = A00.w;
                *(unsigned int*)(pB + 0 * XCP_PITCH + colA) = A01.x;
                *(unsigned int*)(pB + 1 * XCP_PITCH + colA) = A01.y;
                *(unsigned int*)(pB + 2 * XCP_PITCH + colA) = A01.z;
                *(unsigned int*)(pB + 3 * XCP_PITCH + colA) = A01.w;
                *(unsigned int*)(pA + 0 * XCP_PITCH + colB) = A10.x;
                *(unsigned int*)(pA + 1 * XCP_PITCH + colB) = A10.y;
                *(unsigned int*)(pA + 2 * XCP_PITCH + colB) = A10.z;
                *(unsigned int*)(pA + 3 * XCP_PITCH + colB) = A10.w;
                *(unsigned int*)(pB + 0 * XCP_PITCH + colB) = A11.x;
                *(unsigned int*)(pB + 1 * XCP_PITCH + colB) = A11.y;
                *(unsigned int*)(pB + 2 * XCP_PITCH + colB) = A11.z;
                *(unsigned int*)(pB + 3 * XCP_PITCH + colB) = A11.w;
            }

            // Prefetch next chunk's features + norms.
            float nr0, nr1; uint4 B00, B01, B10, B11;
            if (more) {
                nr0 = rn[nc0]; nr1 = rn[nc1];
                B00 = xh4[(size_t)nc0 * 8 + q];
                B01 = xh4[(size_t)nc0 * 8 + 4 + q];
                B10 = xh4[(size_t)nc1 * 8 + q];
                B11 = xh4[(size_t)nc1 * 8 + 4 + q];
            } else {
                nr0 = rc0; nr1 = rc1;
                B00 = A00; B01 = A01; B10 = A10; B11 = A11;
            }

            // Column norms for this lane's 8 edges (pull by edge index lo4').
            float rA0 = __shfl(rc0, 4*q + 0), rA1 = __shfl(rc0, 4*q + 1);
            float rA2 = __shfl(rc0, 4*q + 2), rA3 = __shfl(rc0, 4*q + 3);
            float rB0 = __shfl(rc1, 4*q + 0), rB1 = __shfl(rc1, 4*q + 1);
            float rB2 = __shfl(rc1, 4*q + 2), rB3 = __shfl(rc1, 4*q + 3);

            int eA = base + 4 * q, eB = eA + 16;
            float wA0 = (eA+0 >= blo && eA+0 < bhi) ? __expf(brn * rA0 * z0[0] - shift) : 0.f;
            float wA1 = (eA+1 >= blo && eA+1 < bhi) ? __expf(brn * rA1 * z0[1] - shift) : 0.f;
            float wA2 = (eA+2 >= blo && eA+2 < bhi) ? __expf(brn * rA2 * z0[2] - shift) : 0.f;
            float wA3 = (eA+3 >= blo && eA+3 < bhi) ? __expf(brn * rA3 * z0[3] - shift) : 0.f;
            float wB0 = (eB+0 >= blo && eB+0 < bhi) ? __expf(brn * rB0 * z1[0] - shift) : 0.f;
            float wB1 = (eB+1 >= blo && eB+1 < bhi) ? __expf(brn * rB1 * z1[1] - shift) : 0.f;
            float wB2 = (eB+2 >= blo && eB+2 < bhi) ? __expf(brn * rB2 * z1[2] - shift) : 0.f;
            float wB3 = (eB+3 >= blo && eB+3 < bhi) ? __expf(brn * rB3 * z1[3] - shift) : 0.f;
            lsum += ((wA0 + wA1) + (wA2 + wA3)) + ((wB0 + wB1) + (wB2 + wB3));

            // P-dance: assemble A-fragment P[row lo4][edges 8q..8q+7] in-register.
            //   q0: d-packs of {self, ^16};  q1: d-packs of {q'2, q'3};
            //   q2: e-packs of {q'0, q'1};   q3: e-packs of {^16, self}.
            unsigned d0 = pkh(wA0, wA1), d1 = pkh(wA2, wA3);   // edges 4q+0..3
            unsigned e0 = pkh(wB0, wB1), e1 = pkh(wB2, wB3);   // edges 16+4q+0..3
            unsigned uA0 = __shfl((int)d0, srcA), uA1 = __shfl((int)d1, srcA);
            unsigned uB0 = __shfl((int)d0, srcB), uB1 = __shfl((int)d1, srcB);
            unsigned vA0 = __shfl((int)e0, srcA), vA1 = __shfl((int)e1, srcA);
            unsigned vB0 = __shfl((int)e0, srcB), vB1 = __shfl((int)e1, srcB);
            uint4 pu;
            if (q < 2) { pu.x = uA0; pu.y = uA1; pu.z = uB0; pu.w = uB1; }
            else       { pu.x = vA0; pu.y = vA1; pu.z = vB0; pu.w = vB1; }
            v8h pah = u2h8(pu);

            {
                const char* rp = XCP + (0 + (lo4 >> 1)) * XCP_PITCH + q * 32;
                uint4 da = *(const uint4*)rp;
                uint4 db = *(const uint4*)(rp + 16);
                uint4 bb = { __builtin_amdgcn_perm(da.y, da.x, selp),
                             __builtin_amdgcn_perm(da.w, da.z, selp),
                             __builtin_amdgcn_perm(db.y, db.x, selp),
                             __builtin_amdgcn_perm(db.w, db.z, selp) };
                o0 = __builtin_amdgcn_mfma_f32_16x16x32_f16(pah, u2h8(bb), o0, 0, 0, 0);
            }
            {
                const char* rp = XCP + (8 + (lo4 >> 1)) * XCP_PITCH + q * 32;
                uint4 da = *(const uint4*)rp;
                uint4 db = *(const uint4*)(rp + 16);
                uint4 bb = { __builtin_amdgcn_perm(da.y, da.x, selp),
                             __builtin_amdgcn_perm(da.w, da.z, selp),
                             __builtin_amdgcn_perm(db.y, db.x, selp),
                             __builtin_amdgcn_perm(db.w, db.z, selp) };
                o1 = __builtin_amdgcn_mfma_f32_16x16x32_f16(pah, u2h8(bb), o1, 0, 0, 0);
            }
            {
                const char* rp = XCP + (16 + (lo4 >> 1)) * XCP_PITCH + q * 32;
                uint4 da = *(const uint4*)rp;
                uint4 db = *(const uint4*)(rp + 16);
                uint4 bb = { __builtin_amdgcn_perm(da.y, da.x, selp),
                             __builtin_amdgcn_perm(da.w, da.z, selp),
                             __builtin_amdgcn_perm(db.y, db.x, selp),
                             __builtin_amdgcn_perm(db.w, db.z, selp) };
                o2 = __builtin_amdgcn_mfma_f32_16x16x32_f16(pah, u2h8(bb), o2, 0, 0, 0);
            }
            {
                const char* rp = XCP + (24 + (lo4 >> 1)) * XCP_PITCH + q * 32;
                uint4 da = *(const uint4*)rp;
                uint4 db = *(const uint4*)(rp + 16);
                uint4 bb = { __builtin_amdgcn_perm(da.y, da.x, selp),
                             __builtin_amdgcn_perm(da.w, da.z, selp),
                             __builtin_amdgcn_perm(db.y, db.x, selp),
                             __builtin_amdgcn_perm(db.w, db.z, selp) };
                o3 = __builtin_amdgcn_mfma_f32_16x16x32_f16(pah, u2h8(bb), o3, 0, 0, 0);
            }

            // Rotate pipeline state.
            cc0 = nc0; cc1 = nc1; rc0 = nr0; rc1 = nr1;
            A00 = B00; A01 = B01; A10 = B10; A11 = B11;
        }
    }

    // ---- cross-wave combine: wave1 dumps partials into its own XCP region ----
    // 64 lanes x 68B (o0..o3, pitch 68 keeps banks spread) + 64 x 4B (lsum)
    // = 4352 + 256 = 4608 B, exactly WAVE_LDS.
    if (wid == 1) {
        char* ST = XCP;
        *(v4f*)(ST + lane * 68 +  0) = o0;
        *(v4f*)(ST + lane * 68 + 16) = o1;
        *(v4f*)(ST + lane * 68 + 32) = o2;
        *(v4f*)(ST + lane * 68 + 48) = o3;
        *(float*)(ST + 64 * 68 + lane * 4) = lsum;
    }
    __syncthreads();
    if (wid == 1) return;
    {
        const char* ST = lds_raw + WAVE_LDS;
        o0 += *(const v4f*)(ST + lane * 68 +  0);
        o1 += *(const v4f*)(ST + lane * 68 + 16);
        o2 += *(const v4f*)(ST + lane * 68 + 32);
        o3 += *(const v4f*)(ST + lane * 68 + 48);
        lsum += *(const float*)(ST + 64 * 68 + lane * 4);
    }

    // Row mass lives per-lane (row lo4); reduce across the 4 q-groups.
    lsum += __shfl_xor(lsum, 16, 64);
    lsum += __shfl_xor(lsum, 32, 64);
    float inv = lsum > 0.f ? 1.f / lsum : 0.f;
    // Redistribute to the output layout (rows q*4+reg).
    float i0 = __shfl(inv, 4*q + 0);
    float i1 = __shfl(inv, 4*q + 1);
    float i2 = __shfl(inv, 4*q + 2);
    float i3 = __shfl(inv, 4*q + 3);

    int m0 = t0 + q * 4;
    if (m0 + 0 < n_nodes) { float* p = out + (size_t)(m0 + 0) * 64 + lo4;
        p[0] = o0[0]*i0; p[16] = o1[0]*i0; p[32] = o2[0]*i0; p[48] = o3[0]*i0; }
    if (m0 + 1 < n_nodes) { float* p = out + (size_t)(m0 + 1) * 64 + lo4;
        p[0] = o0[1]*i1; p[16] = o1[1]*i1; p[32] = o2[1]*i1; p[48] = o3[1]*i1; }
    if (m0 + 2 < n_nodes) { float* p = out + (size_t)(m0 + 2) * 64 + lo4;
        p[0] = o0[2]*i2; p[16] = o1[2]*i2; p[32] = o2[2]*i2; p[48] = o3[2]*i2; }
    if (m0 + 3 < n_nodes) { float* p = out + (size_t)(m0 + 3) * 64 + lo4;
        p[0] = o0[3]*i3; p[16] = o1[3]*i3; p[32] = o2[3]*i3; p[48] = o3[3]*i3; }
}

extern "C" void kernel_launch(void* const* d_in, const int* in_sizes, int n_in,
                              void* d_out, int out_size, void* d_ws, size_t ws_size,
                              hipStream_t stream) {
    const float* x        = (const float*)d_in[0];
    const float* beta     = (const float*)d_in[1];
    const int*   edge_row = (const int*)d_in[2];
    const int*   edge_col = (const int*)d_in[3];
    float* out = (float*)d_out;

    int n_nodes = in_sizes[0] / D_FEAT;
    int n_edges = in_sizes[2];

    char* ws = (char*)d_ws;
    float* rn = (float*)ws;
    size_t off0 = ((size_t)n_nodes * sizeof(float) + 255) & ~(size_t)255;
    int* row_ptr = (int*)(ws + off0);
    size_t off1 = off0 + (((size_t)(n_nodes + 1) * sizeof(int) + 255) & ~(size_t)255);
    uint2* xh = (uint2*)(ws + off1);

    {
        int nb_prep = (n_nodes * 16 + 255) / 256;
        int nb_rp   = (n_edges + 255) / 256;
        agnn_prep<<<nb_prep + nb_rp, 256, 0, stream>>>(
            x, rn, xh, edge_row, row_ptr, n_nodes, n_edges, nb_prep);
    }
    {
        int tiles = (n_nodes + 15) / 16;
        agnn_fused<<<tiles, 128, 0, stream>>>(beta, edge_col, row_ptr,
                                              rn, (const uint4*)xh, out, n_nodes);
    }
}